// Round 15
// baseline (130.779 us; speedup 1.0000x reference)
//
#include <hip/hip_runtime.h>
#include <hip/hip_cooperative_groups.h>
#include <stdint.h>

namespace cg = cooperative_groups;

// ---------------- problem constants ----------------
#define B_ROWS 16384
#define NF 26
#define NV 100000
#define ND 13
#define NH 400
#define XPAD 448     // GEMM1 K padded (14 tiles of 32)
#define ZPAD 416     // GEMM2 K padded (13 tiles of 32)
#define Z1S  424     // z1 LDS row stride (shorts): 848B -> 2-way banks = free
#define EPS 1e-5f

typedef __attribute__((ext_vector_type(8))) short short8;
typedef __attribute__((ext_vector_type(4))) float f32x4;
typedef __attribute__((ext_vector_type(4))) unsigned int uint4v;

__device__ inline float bf2f(unsigned short u) {
    union { unsigned int i; float f; } v; v.i = (unsigned int)u << 16; return v.f;
}
__device__ inline unsigned short f2bf(float f) {
    union { float f; unsigned int i; } v; v.f = f;
    return (unsigned short)((v.i + 0x7fff + ((v.i >> 16) & 1)) >> 16);
}

// direct global->LDS DMA; one call = 64 lanes x 16B = 1024B at dest base
typedef __attribute__((address_space(1))) const unsigned int g_u32;
typedef __attribute__((address_space(3))) unsigned int l_u32;
__device__ __forceinline__ void gload_lds16(const void* g, void* l) {
    __builtin_amdgcn_global_load_lds((g_u32*)g, (l_u32*)l, 16, 0, 0);
}

// ---------------- ws layout (bytes) ----------------
#define X_OFF    0
#define W1S_OFF  14680064
#define W2S_OFF  15081472
#define BASE_OFF 15454208
#define ST_OFF   15519744

// =====================================================================
// gather (blocks 0..1023) + W-staging/stat-zero (blocks 1024..1212)
// (R5/R11-proven, unchanged)
// =====================================================================
__global__ __launch_bounds__(256) void gather_prep(
    const int* __restrict__ Xcat, const float* __restrict__ Xdense,
    const float* __restrict__ fm1, const float* __restrict__ emb,
    const float* __restrict__ Wd, const float* __restrict__ bd,
    const float* __restrict__ W1, const float* __restrict__ W2,
    unsigned short* __restrict__ X, float* __restrict__ base,
    unsigned short* __restrict__ W1s, unsigned short* __restrict__ W2s,
    float* __restrict__ st)
{
    int tid = threadIdx.x;
    if (blockIdx.x >= 1024) {
        int c = (blockIdx.x - 1024) * 256 + tid;     // 0..48383
        if (c < 256) {
            for (int i = tid; i < 6656; i += 256) st[i] = 0.f;  // 4 replicas
        }
        const float* W; unsigned short* dst; int K; int cc;
        if (c < 25088) { W = W1; dst = W1s; K = 429; cc = c; }
        else           { W = W2; dst = W2s; K = 400; cc = c - 25088; }
        int n  = cc % 448;
        int q  = (cc / 448) & 3;
        int kt = cc / 1792;
        unsigned short o[8];
        #pragma unroll
        for (int j = 0; j < 8; ++j) {
            int k = kt * 32 + q * 8 + j;
            float v = (n < NH && k < K) ? W[(size_t)k * NH + n] : 0.f;
            o[j] = f2bf(v);
        }
        *(uint4v*)(dst + (size_t)cc * 8) = *(uint4v*)o;
        return;
    }
    int r = blockIdx.x * 16 + (tid >> 4);
    int k = tid & 15;
    const int* idxp = Xcat + (size_t)r * NF;
    unsigned short* xrow = X + (size_t)r * XPAD;

    float s = 0.f, ss = 0.f;
    #pragma unroll
    for (int f = 0; f < NF; ++f) {
        int idx = idxp[f];
        float v = emb[((size_t)f * NV + idx) * 16 + k];
        s += v; ss += v * v;
        xrow[f * 16 + k] = f2bf(v);
    }
    float fmsum = fm1[(size_t)k * NV + idxp[k]];
    if (k < NF - 16) fmsum += fm1[(size_t)(k + 16) * NV + idxp[k + 16]];
    float dsum = 0.f;
    if (k < ND) {
        float xd = Xdense[(size_t)r * ND + k];
        dsum = xd * Wd[k];
        xrow[NF * 16 + k] = f2bf(xd);
    }
    xrow[429 + k] = 0;
    if (k < 3) xrow[445 + k] = 0;

    float ix = s * s - ss;
    float rf = fmsum, rd = dsum;
    #pragma unroll
    for (int off = 8; off; off >>= 1) {
        ix += __shfl_xor(ix, off, 16);
        rf += __shfl_xor(rf, off, 16);
        rd += __shfl_xor(rd, off, 16);
    }
    if (k == 0) base[r] = 0.5f * ix + rf + rd + bd[0];
}

// =====================================================================
// deepfm_core: cooperative, grid 256 x 512, 1 block/CU (R4-proven shape).
// Block owns 64 rows. Wave wv=(rg<<2)|w4: rg row-half (32 rows, 2x16),
// w4 col quarter (NFW=7,6,6,6). K-loops = R11's barrier-free per-wave
// slices. Z1/Z2 never leave LDS.
// LDS: [0,57344) slices (K1,K2; z2 overlay after K2)
//      [57344,111616) z1 [64][424]
//      [111616,114944) alpha/beta
// =====================================================================
__global__ __launch_bounds__(512, 2) void deepfm_core(
    const unsigned short* __restrict__ X,
    const unsigned short* __restrict__ W1s,
    const unsigned short* __restrict__ W2s,
    const float* __restrict__ b1, const float* __restrict__ g1,
    const float* __restrict__ be1,
    const float* __restrict__ b2, const float* __restrict__ g2,
    const float* __restrict__ be2,
    const float* __restrict__ W3, const float* __restrict__ b3,
    const float* __restrict__ base, float* __restrict__ st,
    float* __restrict__ out)
{
    cg::grid_group grid = cg::this_grid();
    __shared__ __align__(16) char smem[114944];
    unsigned short* slices = (unsigned short*)smem;
    unsigned short* z1 = (unsigned short*)(smem + 57344);
    float* alpha_s = (float*)(smem + 111616);
    float* beta_s  = alpha_s + 416;
    unsigned short* z2 = (unsigned short*)smem;    // overlay post-K2

    const int tid = threadIdx.x, bid = blockIdx.x;
    const int lane = tid & 63, wv = tid >> 6;
    const int rg = wv >> 2, w4 = wv & 3;
    const int l15 = lane & 15, qh = lane >> 4;
    const int cb = (w4 == 0) ? 0 : (112 + (w4 - 1) * 96);
    const int NFW = (w4 == 0) ? 7 : 6;
    unsigned short* slice = slices + wv * 3584;    // 7168B/wave
    const int arowA = bid * 64 + rg * 32 + l15;
    const int arowB = arowA + 16;
    float* stc = st + (bid & 3) * 1664;

    auto stageW = [&](const unsigned short* Wst, int kt) {
        #pragma unroll
        for (int i = 0; i < 7; ++i) if (i < NFW) {
            int ci = (kt * 4 + qh) * 448 + cb + i * 16 + l15;
            gload_lds16(Wst + (size_t)ci * 8, slice + i * 512);
        }
    };

    f32x4 acc0[7], acc1[7];
    #pragma unroll
    for (int i = 0; i < 7; ++i) { acc0[i] = f32x4{0,0,0,0}; acc1[i] = f32x4{0,0,0,0}; }

    // ================= K1: z1 = X @ W1 + b1 =================
    stageW(W1s, 0);
    short8 afA_n = *(const short8*)(X + (size_t)arowA * XPAD + qh * 8);
    short8 afB_n = *(const short8*)(X + (size_t)arowB * XPAD + qh * 8);

    for (int kt = 0; kt < 14; ++kt) {
        asm volatile("s_waitcnt vmcnt(0)" ::: "memory");
        __builtin_amdgcn_sched_barrier(0);
        short8 bf[7];
        #pragma unroll
        for (int i = 0; i < 7; ++i) if (i < NFW)
            bf[i] = *(const short8*)(slice + i * 512 + lane * 8);
        short8 afA = afA_n, afB = afB_n;
        asm volatile("s_waitcnt lgkmcnt(0)" ::: "memory");
        __builtin_amdgcn_sched_barrier(0);
        if (kt + 1 < 14) {
            stageW(W1s, kt + 1);
            afA_n = *(const short8*)(X + (size_t)arowA * XPAD + (kt + 1) * 32 + qh * 8);
            afB_n = *(const short8*)(X + (size_t)arowB * XPAD + (kt + 1) * 32 + qh * 8);
        }
        #pragma unroll
        for (int i = 0; i < 7; ++i) if (i < NFW) {
            acc0[i] = __builtin_amdgcn_mfma_f32_16x16x32_bf16(afA, bf[i], acc0[i], 0, 0, 0);
            acc1[i] = __builtin_amdgcn_mfma_f32_16x16x32_bf16(afB, bf[i], acc1[i], 0, 0, 0);
        }
    }

    // K1 epilogue: z1 -> LDS (disjoint region, no barrier needed), stats1
    #pragma unroll
    for (int i = 0; i < 7; ++i) if (i < NFW) {
        int col = cb + i * 16 + l15;
        float bv = b1[col];
        float ps = 0.f, pq = 0.f;
        #pragma unroll
        for (int q = 0; q < 4; ++q) {
            float v0 = acc0[i][q] + bv;
            float v1 = acc1[i][q] + bv;
            z1[(size_t)(rg * 32 + qh * 4 + q) * Z1S + col] = f2bf(v0);
            z1[(size_t)(rg * 32 + 16 + qh * 4 + q) * Z1S + col] = f2bf(v1);
            ps += v0 + v1; pq += v0 * v0 + v1 * v1;
        }
        ps += __shfl_xor(ps, 16, 64); ps += __shfl_xor(ps, 32, 64);
        pq += __shfl_xor(pq, 16, 64); pq += __shfl_xor(pq, 32, 64);
        if (qh == 0) { atomicAdd(&stc[col], ps); atomicAdd(&stc[416 + col], pq); }
    }
    if (w4 == 3) {   // zero-pad z1 cols 400..415 (this rg's 32 rows)
        #pragma unroll
        for (int rr = 0; rr < 8; ++rr)
            z1[(size_t)(rg * 32 + rr * 4 + qh) * Z1S + 400 + l15] = 0;
    }
    grid.sync();     // stats1 complete grid-wide (also block-barriers z1)

    // ================= BN1 finalize =================
    for (int c = tid; c < ZPAD; c += 512) {
        float a = 0.f, b = 0.f;
        if (c < NH) {
            float gs = 0.f, gq = 0.f;
            #pragma unroll
            for (int cp = 0; cp < 4; ++cp) {
                gs += st[cp * 1664 + c];
                gq += st[cp * 1664 + 416 + c];
            }
            float mean = gs * (1.f / 16384.f);
            float var  = gq * (1.f / 16384.f) - mean * mean;
            a = g1[c] * rsqrtf(var + EPS);
            b = be1[c] - mean * a;
        }
        alpha_s[c] = a; beta_s[c] = b;
    }
    __syncthreads();

    // ================= K2: z2 = relu(bn1(z1)) @ W2 + b2 =================
    #pragma unroll
    for (int i = 0; i < 7; ++i) { acc0[i] = f32x4{0,0,0,0}; acc1[i] = f32x4{0,0,0,0}; }
    stageW(W2s, 0);

    for (int kt = 0; kt < 13; ++kt) {
        asm volatile("s_waitcnt vmcnt(0)" ::: "memory");
        __builtin_amdgcn_sched_barrier(0);
        short8 bf[7];
        #pragma unroll
        for (int i = 0; i < 7; ++i) if (i < NFW)
            bf[i] = *(const short8*)(slice + i * 512 + lane * 8);
        int k0 = kt * 32 + qh * 8;
        short8 rA = *(const short8*)&z1[(size_t)(rg * 32 + l15) * Z1S + k0];
        short8 rB = *(const short8*)&z1[(size_t)(rg * 32 + 16 + l15) * Z1S + k0];
        asm volatile("s_waitcnt lgkmcnt(0)" ::: "memory");
        __builtin_amdgcn_sched_barrier(0);
        if (kt + 1 < 13) stageW(W2s, kt + 1);
        short8 afA, afB;
        #pragma unroll
        for (int j = 0; j < 8; ++j) {
            float al = alpha_s[k0 + j], bt = beta_s[k0 + j];
            afA[j] = (short)f2bf(fmaxf(0.f, al * bf2f((unsigned short)rA[j]) + bt));
            afB[j] = (short)f2bf(fmaxf(0.f, al * bf2f((unsigned short)rB[j]) + bt));
        }
        #pragma unroll
        for (int i = 0; i < 7; ++i) if (i < NFW) {
            acc0[i] = __builtin_amdgcn_mfma_f32_16x16x32_bf16(afA, bf[i], acc0[i], 0, 0, 0);
            acc1[i] = __builtin_amdgcn_mfma_f32_16x16x32_bf16(afB, bf[i], acc1[i], 0, 0, 0);
        }
    }

    __syncthreads();   // all waves done with slices before z2 overlays them
    // K2 epilogue: z2 -> LDS, stats2
    #pragma unroll
    for (int i = 0; i < 7; ++i) if (i < NFW) {
        int col = cb + i * 16 + l15;
        float bv = b2[col];
        float ps = 0.f, pq = 0.f;
        #pragma unroll
        for (int q = 0; q < 4; ++q) {
            float v0 = acc0[i][q] + bv;
            float v1 = acc1[i][q] + bv;
            z2[(size_t)(rg * 32 + qh * 4 + q) * 400 + col] = f2bf(v0);
            z2[(size_t)(rg * 32 + 16 + qh * 4 + q) * 400 + col] = f2bf(v1);
            ps += v0 + v1; pq += v0 * v0 + v1 * v1;
        }
        ps += __shfl_xor(ps, 16, 64); ps += __shfl_xor(ps, 32, 64);
        pq += __shfl_xor(pq, 16, 64); pq += __shfl_xor(pq, 32, 64);
        if (qh == 0) { atomicAdd(&stc[832 + col], ps); atomicAdd(&stc[1248 + col], pq); }
    }
    grid.sync();     // stats2 complete grid-wide (also block-barriers z2)

    // ================= BN2 + final dot =================
    for (int c = tid; c < NH; c += 512) {
        float gs = 0.f, gq = 0.f;
        #pragma unroll
        for (int cp = 0; cp < 4; ++cp) {
            gs += st[cp * 1664 + 832 + c];
            gq += st[cp * 1664 + 1248 + c];
        }
        float mean = gs * (1.f / 16384.f);
        float var  = gq * (1.f / 16384.f) - mean * mean;
        float a = g2[c] * rsqrtf(var + EPS);
        alpha_s[c] = a;
        beta_s[c]  = be2[c] - mean * a;
    }
    __syncthreads();
    {
        int r = tid >> 3, oct = tid & 7;     // 64 rows x 8 threads
        float facc = 0.f;
        for (int c = oct; c < NH; c += 8)
            facc += fmaxf(0.f, alpha_s[c] * bf2f(z2[(size_t)r * 400 + c]) + beta_s[c]) * W3[c];
        facc += __shfl_xor(facc, 1, 64);
        facc += __shfl_xor(facc, 2, 64);
        facc += __shfl_xor(facc, 4, 64);
        if (oct == 0) out[bid * 64 + r] = base[bid * 64 + r] + facc + b3[0];
    }
}

// =====================================================================
extern "C" void kernel_launch(void* const* d_in, const int* in_sizes, int n_in,
                              void* d_out, int out_size, void* d_ws, size_t ws_size,
                              hipStream_t stream)
{
    const int*   Xcat = (const int*)d_in[0];
    const float* Xd   = (const float*)d_in[1];
    const float* fm1  = (const float*)d_in[2];
    const float* emb  = (const float*)d_in[3];
    const float* Wd   = (const float*)d_in[4];
    const float* bd   = (const float*)d_in[5];
    const float* W1   = (const float*)d_in[6];
    const float* b1   = (const float*)d_in[7];
    const float* g1   = (const float*)d_in[8];
    const float* be1  = (const float*)d_in[9];
    const float* W2   = (const float*)d_in[10];
    const float* b2   = (const float*)d_in[11];
    const float* g2   = (const float*)d_in[12];
    const float* be2  = (const float*)d_in[13];
    const float* W3   = (const float*)d_in[14];
    const float* b3   = (const float*)d_in[15];

    char* ws = (char*)d_ws;
    unsigned short* X   = (unsigned short*)(ws + X_OFF);
    unsigned short* W1s = (unsigned short*)(ws + W1S_OFF);
    unsigned short* W2s = (unsigned short*)(ws + W2S_OFF);
    float* base = (float*)(ws + BASE_OFF);
    float* st   = (float*)(ws + ST_OFF);
    float* out  = (float*)d_out;

    // 1: gather + W staging + 4-replica stat zero
    gather_prep<<<1213, 256, 0, stream>>>(Xcat, Xd, fm1, emb, Wd, bd, W1, W2,
                                          X, base, W1s, W2s, st);

    // 2: K1 -> BN1 -> K2 -> BN2 -> final, Z1/Z2 in LDS, cooperative
    void* args[] = {
        (void*)&X, (void*)&W1s, (void*)&W2s,
        (void*)&b1, (void*)&g1, (void*)&be1,
        (void*)&b2, (void*)&g2, (void*)&be2,
        (void*)&W3, (void*)&b3,
        (void*)&base, (void*)&st, (void*)&out
    };
    hipLaunchCooperativeKernel((const void*)deepfm_core, dim3(256), dim3(512),
                               args, 0, stream);
}

// Round 16
// 72.497 us; speedup vs baseline: 1.8039x; 1.8039x over previous
//
#include <hip/hip_runtime.h>
#include <stdint.h>

// ---------------- problem constants ----------------
#define B_ROWS 16384
#define NF 26
#define NV 100000
#define ND 13
#define NH 400
#define XPAD 448     // GEMM1 K padded (14 tiles of 32)
#define ZPAD 416     // GEMM2 K padded (13 tiles of 32)
#define EPS 1e-5f

typedef __attribute__((ext_vector_type(8))) short short8;
typedef __attribute__((ext_vector_type(4))) float f32x4;
typedef __attribute__((ext_vector_type(4))) unsigned int uint4v;

__device__ inline float bf2f(unsigned short u) {
    union { unsigned int i; float f; } v; v.i = (unsigned int)u << 16; return v.f;
}
__device__ inline unsigned short f2bf(float f) {
    union { float f; unsigned int i; } v; v.f = f;
    return (unsigned short)((v.i + 0x7fff + ((v.i >> 16) & 1)) >> 16);
}

// direct global->LDS DMA; one call = 64 lanes x 16B = 1024B at dest base
typedef __attribute__((address_space(1))) const unsigned int g_u32;
typedef __attribute__((address_space(3))) unsigned int l_u32;
__device__ __forceinline__ void gload_lds16(const void* g, void* l) {
    __builtin_amdgcn_global_load_lds((g_u32*)g, (l_u32*)l, 16, 0, 0);
}

// ---------------- ws layout (bytes) ----------------
#define X_OFF    0
#define Z1_OFF   14680064
#define W1S_OFF  28311552
#define W2S_OFF  28712960
#define BASE_OFF 29085696
#define ST_OFF   29151232

// =====================================================================
// gather (blocks 0..1023) + W-staging/stat-zero (blocks 1024..1212)
// (R5/R11-proven, unchanged)
// =====================================================================
__global__ __launch_bounds__(256) void gather_prep(
    const int* __restrict__ Xcat, const float* __restrict__ Xdense,
    const float* __restrict__ fm1, const float* __restrict__ emb,
    const float* __restrict__ Wd, const float* __restrict__ bd,
    const float* __restrict__ W1, const float* __restrict__ W2,
    unsigned short* __restrict__ X, float* __restrict__ base,
    unsigned short* __restrict__ W1s, unsigned short* __restrict__ W2s,
    float* __restrict__ st)
{
    int tid = threadIdx.x;
    if (blockIdx.x >= 1024) {
        int c = (blockIdx.x - 1024) * 256 + tid;     // 0..48383
        if (c < 256) {
            for (int i = tid; i < 6656; i += 256) st[i] = 0.f;  // 4 replicas
        }
        const float* W; unsigned short* dst; int K; int cc;
        if (c < 25088) { W = W1; dst = W1s; K = 429; cc = c; }
        else           { W = W2; dst = W2s; K = 400; cc = c - 25088; }
        int n  = cc % 448;
        int q  = (cc / 448) & 3;
        int kt = cc / 1792;
        unsigned short o[8];
        #pragma unroll
        for (int j = 0; j < 8; ++j) {
            int k = kt * 32 + q * 8 + j;
            float v = (n < NH && k < K) ? W[(size_t)k * NH + n] : 0.f;
            o[j] = f2bf(v);
        }
        *(uint4v*)(dst + (size_t)cc * 8) = *(uint4v*)o;
        return;
    }
    int r = blockIdx.x * 16 + (tid >> 4);
    int k = tid & 15;
    const int* idxp = Xcat + (size_t)r * NF;
    unsigned short* xrow = X + (size_t)r * XPAD;

    float s = 0.f, ss = 0.f;
    #pragma unroll
    for (int f = 0; f < NF; ++f) {
        int idx = idxp[f];
        float v = emb[((size_t)f * NV + idx) * 16 + k];
        s += v; ss += v * v;
        xrow[f * 16 + k] = f2bf(v);
    }
    float fmsum = fm1[(size_t)k * NV + idxp[k]];
    if (k < NF - 16) fmsum += fm1[(size_t)(k + 16) * NV + idxp[k + 16]];
    float dsum = 0.f;
    if (k < ND) {
        float xd = Xdense[(size_t)r * ND + k];
        dsum = xd * Wd[k];
        xrow[NF * 16 + k] = f2bf(xd);
    }
    xrow[429 + k] = 0;
    if (k < 3) xrow[445 + k] = 0;

    float ix = s * s - ss;
    float rf = fmsum, rd = dsum;
    #pragma unroll
    for (int off = 8; off; off >>= 1) {
        ix += __shfl_xor(ix, off, 16);
        rf += __shfl_xor(rf, off, 16);
        rd += __shfl_xor(rd, off, 16);
    }
    if (k == 0) base[r] = 0.5f * ix + rf + rd + bd[0];
}

// =====================================================================
// gemm_v5: R11's barrier-free per-wave GEMM + T4 pipelining:
// double-buffered per-wave slices, counted vmcnt(N) so tile kt+1's DMAs
// stay in flight across tile kt's whole phase. grid 256 x 512.
// Wave wv=(rg<<2)|w4: rows bid*64+rg*32 (2x16), col quarter w4 (7,6,6,6).
// Per-tile VMEM ops/wave = NFW+2 (W DMAs + 2 A loads) -> wait vmcnt(9|8).
// =====================================================================
template<int NT, int LDA, bool APPLY_BN>
__global__ __launch_bounds__(512, 2) void gemm_v5(
    const unsigned short* __restrict__ A,
    const unsigned short* __restrict__ Wst,
    const float* __restrict__ bias,
    const float* __restrict__ st_all,
    const float* __restrict__ g, const float* __restrict__ be,
    unsigned short* __restrict__ Z, int ldz, int padZ,
    float* __restrict__ st_out, int sumOff, int sqOff)
{
    __shared__ __align__(16) unsigned short slices[51200];  // 2 bufs x 25600
    __shared__ float alpha_s[416], beta_s[416];

    const int tid = threadIdx.x, bid = blockIdx.x;
    const int lane = tid & 63, wv = tid >> 6;
    const int rg = wv >> 2, w4 = wv & 3;
    const int l15 = lane & 15, qh = lane >> 4;
    const int cb = (w4 == 0) ? 0 : (112 + (w4 - 1) * 96);
    const int NFW = (w4 == 0) ? 7 : 6;
    const int soff = rg * 12800 + ((w4 == 0) ? 0 : (3584 + (w4 - 1) * 3072));
    const int arowA = bid * 64 + rg * 32 + l15;
    const int arowB = arowA + 16;

    if constexpr (APPLY_BN) {
        if (tid < 416) {
            int c = tid;
            float a = 0.f, b = 0.f;
            if (c < NH) {
                float gs = 0.f, gq = 0.f;
                #pragma unroll
                for (int cp = 0; cp < 4; ++cp) {
                    gs += st_all[cp * 1664 + c];
                    gq += st_all[cp * 1664 + 416 + c];
                }
                float mean = gs * (1.f / 16384.f);
                float var  = gq * (1.f / 16384.f) - mean * mean;
                a = g[c] * rsqrtf(var + EPS);
                b = be[c] - mean * a;
            }
            alpha_s[c] = a; beta_s[c] = b;
        }
        __syncthreads();
    }

    f32x4 acc0[7], acc1[7];
    #pragma unroll
    for (int i = 0; i < 7; ++i) { acc0[i] = f32x4{0,0,0,0}; acc1[i] = f32x4{0,0,0,0}; }

    auto stageW = [&](int kt, int buf) {
        unsigned short* sl = slices + buf * 25600 + soff;
        #pragma unroll
        for (int i = 0; i < 7; ++i) if (i < NFW) {
            int ci = (kt * 4 + qh) * 448 + cb + i * 16 + l15;
            gload_lds16(Wst + (size_t)ci * 8, sl + i * 512);
        }
    };
    auto ldA = [&](int kt, short8& a, short8& b) {
        a = *(const short8*)(A + (size_t)arowA * LDA + kt * 32 + qh * 8);
        b = *(const short8*)(A + (size_t)arowB * LDA + kt * 32 + qh * 8);
    };
    auto waitN = [&]() {
        if (w4 == 0) asm volatile("s_waitcnt vmcnt(9)" ::: "memory");
        else         asm volatile("s_waitcnt vmcnt(8)" ::: "memory");
        __builtin_amdgcn_sched_barrier(0);
    };
    auto wait0 = [&]() {
        asm volatile("s_waitcnt vmcnt(0)" ::: "memory");
        __builtin_amdgcn_sched_barrier(0);
    };
    auto waitlg = [&]() {
        asm volatile("s_waitcnt lgkmcnt(0)" ::: "memory");
        __builtin_amdgcn_sched_barrier(0);
    };

    // phase: consume tile kt from buf; optionally issue tile kt+2 into buf.
    auto phase = [&](int kt, int buf, bool last, bool issue,
                     short8& afA, short8& afB) {
        if (last) wait0(); else waitN();     // tile kt's W-DMAs + A-loads done
        const unsigned short* sl = slices + buf * 25600 + soff;
        short8 bf[7];
        #pragma unroll
        for (int i = 0; i < 7; ++i) if (i < NFW)
            bf[i] = *(const short8*)(sl + i * 512 + lane * 8);
        short8 aA = afA, aB = afB;           // copy before regs are reloaded
        waitlg();                             // ds_reads retired -> buf reusable
        if (issue) { stageW(kt + 2, buf); ldA(kt + 2, afA, afB); }
        if constexpr (APPLY_BN) {
            const int k0 = kt * 32 + qh * 8;
            #pragma unroll
            for (int j = 0; j < 8; ++j) {
                float al = alpha_s[k0 + j], bt = beta_s[k0 + j];
                aA[j] = (short)f2bf(fmaxf(0.f, al * bf2f((unsigned short)aA[j]) + bt));
                aB[j] = (short)f2bf(fmaxf(0.f, al * bf2f((unsigned short)aB[j]) + bt));
            }
        }
        #pragma unroll
        for (int i = 0; i < 7; ++i) if (i < NFW) {
            acc0[i] = __builtin_amdgcn_mfma_f32_16x16x32_bf16(aA, bf[i], acc0[i], 0, 0, 0);
            acc1[i] = __builtin_amdgcn_mfma_f32_16x16x32_bf16(aB, bf[i], acc1[i], 0, 0, 0);
        }
    };

    short8 afA0, afB0, afA1, afB1;
    stageW(0, 0); ldA(0, afA0, afB0);        // prologue: tiles 0,1 in flight
    stageW(1, 1); ldA(1, afA1, afB1);

    int kt2 = 0;
    for (; kt2 + 3 < NT; kt2 += 2) {
        phase(kt2,     0, false, true, afA0, afB0);
        phase(kt2 + 1, 1, false, true, afA1, afB1);
    }
    if constexpr (NT % 2 == 0) {
        phase(NT - 2, 0, false, false, afA0, afB0);
        phase(NT - 1, 1, true,  false, afA1, afB1);
    } else {
        phase(NT - 3, 0, false, true,  afA0, afB0);   // issues NT-1 into buf0
        phase(NT - 2, 1, false, false, afA1, afB1);
        phase(NT - 1, 0, true,  false, afA0, afB0);
    }

    // ---- epilogue: +bias, bf16 store, per-wave stats -> replica atomics ----
    float* stc = st_out + (bid & 3) * 1664;
    #pragma unroll
    for (int i = 0; i < 7; ++i) if (i < NFW) {
        int col = cb + i * 16 + l15;
        float bv = bias[col];
        float ps = 0.f, pq = 0.f;
        #pragma unroll
        for (int q = 0; q < 4; ++q) {
            float v0 = acc0[i][q] + bv;
            float v1 = acc1[i][q] + bv;
            Z[(size_t)(bid * 64 + rg * 32 + qh * 4 + q) * ldz + col] = f2bf(v0);
            Z[(size_t)(bid * 64 + rg * 32 + 16 + qh * 4 + q) * ldz + col] = f2bf(v1);
            ps += v0 + v1; pq += v0 * v0 + v1 * v1;
        }
        ps += __shfl_xor(ps, 16, 64); ps += __shfl_xor(ps, 32, 64);
        pq += __shfl_xor(pq, 16, 64); pq += __shfl_xor(pq, 32, 64);
        if (qh == 0) {
            atomicAdd(&stc[sumOff + col], ps);
            atomicAdd(&stc[sqOff + col], pq);
        }
    }
    if (padZ && w4 == 3) {   // zero cols 400..415 (this rg's 32 rows)
        #pragma unroll
        for (int rr = 0; rr < 8; ++rr)
            Z[(size_t)(bid * 64 + rg * 32 + rr * 4 + qh) * ldz + 400 + l15] = 0;
    }
}

// =====================================================================
// final: BN2 from replicas, then out[r] = base[r] + relu(.)·W3 + b3
// =====================================================================
__global__ __launch_bounds__(256) void final_kernel(
    const unsigned short* __restrict__ Z2,
    const float* __restrict__ st_all,
    const float* __restrict__ g2, const float* __restrict__ be2,
    const float* __restrict__ W3, const float* __restrict__ b3,
    const float* __restrict__ base, float* __restrict__ out)
{
    __shared__ float a2s[NH], b2s[NH], w3s[NH];
    int tid = threadIdx.x;
    for (int c = tid; c < NH; c += 256) {
        float gs = 0.f, gq = 0.f;
        #pragma unroll
        for (int cp = 0; cp < 4; ++cp) {
            gs += st_all[cp * 1664 + 832 + c];
            gq += st_all[cp * 1664 + 1248 + c];
        }
        float mean = gs * (1.f / 16384.f);
        float var  = gq * (1.f / 16384.f) - mean * mean;
        float a = g2[c] * rsqrtf(var + EPS);
        a2s[c] = a;
        b2s[c] = be2[c] - mean * a;
        w3s[c] = W3[c];
    }
    __syncthreads();
    int lane = tid & 63;
    int wv = tid >> 6;
    bool act = lane < 50;
    int cb = lane * 8;
    float al[8], bb[8], w3[8];
    #pragma unroll
    for (int j = 0; j < 8; ++j) {
        al[j] = act ? a2s[cb + j] : 0.f;
        bb[j] = act ? b2s[cb + j] : 0.f;
        w3[j] = act ? w3s[cb + j] : 0.f;
    }
    int r0 = blockIdx.x * 32 + wv * 8;
    float bias3 = b3[0];
    for (int t = 0; t < 8; t += 2) {
        int r = r0 + t;
        float acc0 = 0.f, acc1 = 0.f;
        if (act) {
            short8 z0 = *(const short8*)(Z2 + (size_t)r * ZPAD + cb);
            short8 z1 = *(const short8*)(Z2 + (size_t)(r + 1) * ZPAD + cb);
            #pragma unroll
            for (int j = 0; j < 8; ++j) {
                acc0 += fmaxf(0.f, al[j] * bf2f((unsigned short)z0[j]) + bb[j]) * w3[j];
                acc1 += fmaxf(0.f, al[j] * bf2f((unsigned short)z1[j]) + bb[j]) * w3[j];
            }
        }
        #pragma unroll
        for (int off = 32; off; off >>= 1) {
            acc0 += __shfl_xor(acc0, off, 64);
            acc1 += __shfl_xor(acc1, off, 64);
        }
        if (lane == 0) out[r] = base[r] + acc0 + bias3;
        if (lane == 1) out[r + 1] = base[r + 1] + acc1 + bias3;
    }
}

// =====================================================================
extern "C" void kernel_launch(void* const* d_in, const int* in_sizes, int n_in,
                              void* d_out, int out_size, void* d_ws, size_t ws_size,
                              hipStream_t stream)
{
    const int*   Xcat = (const int*)d_in[0];
    const float* Xd   = (const float*)d_in[1];
    const float* fm1  = (const float*)d_in[2];
    const float* emb  = (const float*)d_in[3];
    const float* Wd   = (const float*)d_in[4];
    const float* bd   = (const float*)d_in[5];
    const float* W1   = (const float*)d_in[6];
    const float* b1   = (const float*)d_in[7];
    const float* g1   = (const float*)d_in[8];
    const float* be1  = (const float*)d_in[9];
    const float* W2   = (const float*)d_in[10];
    const float* b2   = (const float*)d_in[11];
    const float* g2   = (const float*)d_in[12];
    const float* be2  = (const float*)d_in[13];
    const float* W3   = (const float*)d_in[14];
    const float* b3   = (const float*)d_in[15];

    char* ws = (char*)d_ws;
    unsigned short* X   = (unsigned short*)(ws + X_OFF);
    unsigned short* Z1  = (unsigned short*)(ws + Z1_OFF);
    unsigned short* Z2  = X;   // X dead after GEMM1
    unsigned short* W1s = (unsigned short*)(ws + W1S_OFF);
    unsigned short* W2s = (unsigned short*)(ws + W2S_OFF);
    float* base = (float*)(ws + BASE_OFF);
    float* st   = (float*)(ws + ST_OFF);
    float* out  = (float*)d_out;

    // 1: gather + W staging + 4-replica stat zero
    gather_prep<<<1213, 256, 0, stream>>>(Xcat, Xd, fm1, emb, Wd, bd, W1, W2,
                                          X, base, W1s, W2s, st);

    // 2: Z1 = X @ W1 + b1, stats1 (T4-pipelined barrier-free GEMM)
    gemm_v5<14, XPAD, false><<<256, 512, 0, stream>>>(
        X, W1s, b1, nullptr, nullptr, nullptr, Z1, ZPAD, 1, st, 0, 416);

    // 3: Z2 = relu(bn1(Z1)) @ W2 + b2, stats2
    gemm_v5<13, ZPAD, true><<<256, 512, 0, stream>>>(
        Z1, W2s, b2, st, g1, be1, Z2, ZPAD, 0, st, 832, 1248);

    // 4: out = base + relu(bn2(Z2))·W3 + b3
    final_kernel<<<512, 256, 0, stream>>>(Z2, st, g2, be2, W3, b3, base, out);
}